// Round 9
// baseline (30.456 us; speedup 1.0000x reference)
//
#include <hip/hip_runtime.h>
#include <math.h>

#define HH 256
#define WW 256
#define BB 32
#define NW 8  // 256 rows = 8 x u32 words per column bitmask

// ---------------------------------------------------------------------------
// Kernel A: build column bitmasks.  P bit = (pred > 0.5), T bit = (target==1).
// Grid: BB*NW*4 = 1024 blocks; block = (b, word-row j, column-quarter wq).
// ---------------------------------------------------------------------------
__global__ __launch_bounds__(256) void bitmask_kernel(
    const float* __restrict__ pred, const float* __restrict__ tgt,
    unsigned int* __restrict__ P, unsigned int* __restrict__ T) {
  const int b  = blockIdx.x >> 5;
  const int j  = (blockIdx.x >> 2) & 7;
  const int wq = blockIdx.x & 3;
  const int r    = threadIdx.x >> 6;   // wave id: row-subset (8 rows)
  const int lane = threadIdx.x & 63;
  const int col  = wq * 64 + lane;
  const int row0 = j * 32 + r * 8;

  const float* pin = pred + (size_t)b * (HH * WW) + row0 * WW + col;
  const float* tin = tgt  + (size_t)b * (HH * WW) + row0 * WW + col;
  unsigned int pb = 0, tb = 0;
#pragma unroll
  for (int i = 0; i < 8; ++i) {
    pb |= (pin[i * WW] > 0.5f ? 1u : 0u) << i;
    tb |= (tin[i * WW] == 1.0f ? 1u : 0u) << i;
  }

  __shared__ unsigned int sP[4][64], sT[4][64];
  sP[r][lane] = pb << (r * 8);
  sT[r][lane] = tb << (r * 8);
  __syncthreads();
  if (r == 0) {
    P[((size_t)b * NW + j) * WW + col] =
        sP[0][lane] | sP[1][lane] | sP[2][lane] | sP[3][lane];
    T[((size_t)b * NW + j) * WW + col] =
        sT[0][lane] | sT[1][lane] | sT[2][lane] | sT[3][lane];
  }
}

// ---------------------------------------------------------------------------
// Kernel B (STRIPE8): block = (b, 8-row stripe js), 512 threads, 1024 blocks
// -> 4 blocks/CU (32 waves/CU, full occupancy), LDS 32 KB.
//   Phase 1: threads 0-255 (pred) / 256-511 (target): column edge-mask
//     chains for the stripe's 8 rows, seeded by sub-word clz/ctz carries
//     (js block-uniform -> scalar shifts).  Writes PRE-DEMUXED float2
//     {dist-to-1^2, dist-to-0^2} halves of a float4 per (row,col) into LDS.
//   Phase 2: wave wv owns row wv alone; lane owns 4 cols; pure
//     ds_read_b128 + fmin k-loop (exact early exit), ONE shuffle reduce.
// ---------------------------------------------------------------------------
__global__ __launch_bounds__(512) void stripe8_kernel(
    const unsigned int* __restrict__ P, const unsigned int* __restrict__ T,
    float* __restrict__ partial) {
  const int blk = blockIdx.x;          // b*32 + js
  const int b  = blk >> 5;
  const int js = blk & 31;
  const int base = js * 8;             // first row of stripe
  const int wq0 = base >> 5, sub = base & 31;   // block-uniform
  const int tid = threadIdx.x;

  __shared__ float4 sv[8][WW];  // [row-in-stripe][col] = {p1,p0,t1,t0} dist^2

  // ---- phase 1 ----
  {
    const int mp = tid >> 8;           // 0: pred, 1: target
    const int w  = tid & 255;
    const unsigned int* M = mp ? T : P;

    unsigned int Wd[NW];
#pragma unroll
    for (int jj = 0; jj < NW; ++jj)
      Wd[jj] = M[((size_t)b * NW + jj) * WW + w];

    unsigned int E[NW];                // bit p of E[jj] = edge at 32jj+p
#pragma unroll
    for (int jj = 0; jj < NW - 1; ++jj)
      E[jj] = Wd[jj] ^ ((Wd[jj] >> 1) | (Wd[jj + 1] << 31));
    E[NW - 1] = (Wd[NW - 1] ^ (Wd[NW - 1] >> 1)) & 0x7FFFFFFFu;

    // words containing this stripe (wq0 uniform; static selection)
    unsigned int Ew = 0, Ewm1 = 0, Ww = 0;
#pragma unroll
    for (int jj = 0; jj < NW; ++jj) {
      if (jj == wq0) { Ew = E[jj]; Ww = Wd[jj]; }
      if (jj == wq0 - 1) Ewm1 = E[jj];
    }
    // 8-bit windows: EU8 bit i = edge at base+i; EQ8 bit i = edge at base+i-1
    const unsigned int EU8 = (Ew >> sub) & 0xFFu;  // sub<=24: no spill
    const unsigned int EQ8 =
        sub ? ((Ew >> (sub - 1)) & 0xFFu)
            : (((Ew << 1) | (wq0 ? (Ewm1 >> 31) : 0u)) & 0xFFu);
    const unsigned int W8 = (Ww >> sub) & 0xFFu;   // own bits, rows base..+7

    // down-carry: highest edge position < base
    const unsigned int submask = sub ? ((1u << sub) - 1u) : 0u;
    int emax = -100000;
#pragma unroll
    for (int jj = 0; jj < NW; ++jj) {
      unsigned int a = (jj < wq0) ? E[jj]
                                  : ((jj == wq0) ? (E[jj] & submask) : 0u);
      if (a) emax = 32 * jj + 31 - __builtin_clz(a);
    }
    int D = (base - 1) - emax;
    if (D > 513) D = 513;

    // up-carry: lowest edge position >= base+8
    const int r8 = base + 8;
    const int wr = r8 >> 5;
    const unsigned int upmask =
        (r8 & 31) ? ~((1u << (r8 & 31)) - 1u) : 0xFFFFFFFFu;
    int emin = 100000;
#pragma unroll
    for (int jj = NW - 1; jj >= 0; --jj) {
      unsigned int a = (jj > wr) ? E[jj]
                                 : ((jj == wr) ? (E[jj] & upmask) : 0u);
      if (a) emin = 32 * jj + __builtin_ctz(a);
    }
    int U = (emin + 1) - r8;
    if (U > 513) U = 513;

    int dn[8];                         // static idx after unroll
#pragma unroll
    for (int i = 0; i < 8; ++i) {
      D = ((EQ8 >> i) & 1u) ? 1 : (D + 1);
      dn[i] = D;
    }
#pragma unroll
    for (int i = 7; i >= 0; --i) {
      U = ((EU8 >> i) & 1u) ? 1 : (U + 1);
      int g = min(min(dn[i], U), 512); // cap = H+W (exact, incl. empty cols)
      float g2 = (float)(g * g);
      bool own = (W8 >> i) & 1u;
      // demuxed pair: {dist^2 to mask==1, dist^2 to mask==0}
      float2 v = own ? make_float2(0.f, g2) : make_float2(g2, 0.f);
      *(((float2*)&sv[i][w]) + mp) = v;   // mp=0 -> .xy, mp=1 -> .zw
    }
  }
  __syncthreads();

  // ---- phase 2: one row per wave ----
  const int wv = tid >> 6;             // row in stripe
  const int lane = tid & 63;

  float m[4][4];                       // [col-group][map], static idx only
#pragma unroll
  for (int c = 0; c < 4; ++c) {
    float4 v = sv[wv][lane + 64 * c];
    m[c][0] = v.x; m[c][1] = v.y; m[c][2] = v.z; m[c][3] = v.w;
  }

  for (int k = 1; k < WW; ++k) {
    const float c2 = (float)(k * k);
    float mx = 0.f;
#pragma unroll
    for (int c = 0; c < 4; ++c)
      mx = fmaxf(mx, fmaxf(fmaxf(m[c][0], m[c][1]), fmaxf(m[c][2], m[c][3])));
    if (c2 >= mx) break;               // exact: remaining candidates >= k^2
#pragma unroll
    for (int c = 0; c < 4; ++c) {
      const int y = lane + 64 * c;
      const int lo = y - k;
      if (lo >= 0) {
        float4 v = sv[wv][lo];
        m[c][0] = fminf(m[c][0], v.x + c2); m[c][1] = fminf(m[c][1], v.y + c2);
        m[c][2] = fminf(m[c][2], v.z + c2); m[c][3] = fminf(m[c][3], v.w + c2);
      }
      const int hi = y + k;
      if (hi < WW) {
        float4 v = sv[wv][hi];
        m[c][0] = fminf(m[c][0], v.x + c2); m[c][1] = fminf(m[c][1], v.y + c2);
        m[c][2] = fminf(m[c][2], v.z + c2); m[c][3] = fminf(m[c][3], v.w + c2);
      }
    }
  }

  float val = 0.f;
#pragma unroll
  for (int c = 0; c < 4; ++c) {
    float pd = sqrtf(m[c][0]) + sqrtf(m[c][1]);   // pred_dist
    float td = sqrtf(m[c][2]) + sqrtf(m[c][3]);   // target_dist
    float diff = pd - td;
    val += diff * diff * td * td;                 // (pd-td)^2 * td^2
  }
  for (int off = 32; off > 0; off >>= 1) val += __shfl_down(val, off);
  if (lane == 0) partial[blk * 8 + wv] = val;     // 8192 partials
}

// ---------------------------------------------------------------------------
// Kernel C: reduce 8192 partials in double, write mean.
// ---------------------------------------------------------------------------
__global__ __launch_bounds__(256) void finalize_kernel(
    const float* __restrict__ partial, float* __restrict__ out) {
  __shared__ double sd[256];
  double sum = 0.0;
  for (int i = threadIdx.x; i < BB * HH; i += 256) sum += (double)partial[i];
  sd[threadIdx.x] = sum;
  __syncthreads();
  for (int stride = 128; stride > 0; stride >>= 1) {
    if (threadIdx.x < stride) sd[threadIdx.x] += sd[threadIdx.x + stride];
    __syncthreads();
  }
  if (threadIdx.x == 0)
    out[0] = (float)(sd[0] / (double)((size_t)BB * HH * WW));
}

extern "C" void kernel_launch(void* const* d_in, const int* in_sizes, int n_in,
                              void* d_out, int out_size, void* d_ws, size_t ws_size,
                              hipStream_t stream) {
  const float* pred = (const float*)d_in[0];
  const float* tgt  = (const float*)d_in[1];
  float* out = (float*)d_out;

  // ws: P (256 KB), T (256 KB), partial (32 KB)
  unsigned int* P = (unsigned int*)d_ws;
  unsigned int* T = P + (size_t)BB * NW * WW;
  float* partial = (float*)(T + (size_t)BB * NW * WW);

  hipLaunchKernelGGL(bitmask_kernel, dim3(BB * NW * 4), dim3(256), 0, stream,
                     pred, tgt, P, T);
  hipLaunchKernelGGL(stripe8_kernel, dim3(BB * 32), dim3(512), 0, stream,
                     P, T, partial);
  hipLaunchKernelGGL(finalize_kernel, dim3(1), dim3(256), 0, stream,
                     partial, out);
}